// Round 6
// baseline (159.972 us; speedup 1.0000x reference)
//
#include <hip/hip_runtime.h>
#include <hip/hip_bf16.h>
#include <math.h>

#define BB 32
#define NN 512

typedef _Float16 f16x8 __attribute__((ext_vector_type(8)));
typedef __fp16  fp16x2 __attribute__((ext_vector_type(2)));
typedef float f32x4 __attribute__((ext_vector_type(4)));

#define MFMA16(a, b, c) __builtin_amdgcn_mfma_f32_16x16x32_f16(a, b, c, 0, 0, 0)

union AF { f16x8 v; unsigned int u[4]; };

// async global->LDS; LDS dest = wave-uniform base + lane*size
__device__ __forceinline__ void gload_lds16(const void* g, void* l) {
    __builtin_amdgcn_global_load_lds(
        (const __attribute__((address_space(1))) unsigned int*)g,
        (__attribute__((address_space(3))) unsigned int*)l, 16, 0, 0);
}
__device__ __forceinline__ void gload_lds4(const void* g, void* l) {
    __builtin_amdgcn_global_load_lds(
        (const __attribute__((address_space(1))) unsigned int*)g,
        (__attribute__((address_space(3))) unsigned int*)l, 4, 0, 0);
}

// monotonic uint key for fp32 atomicMax (exact max, order-independent)
__device__ __forceinline__ unsigned fenc(float f) {
    unsigned b = __float_as_uint(f);
    return (b & 0x80000000u) ? ~b : (b | 0x80000000u);
}
__device__ __forceinline__ float fdec(unsigned u) {
    return __uint_as_float((u & 0x80000000u) ? (u ^ 0x80000000u) : ~u);
}

// ============ W^T fp16 prep (W0 + W1 fused) + maxd key zero-init ===========
__global__ __launch_bounds__(256) void k_wt_prep(
    const float* __restrict__ W0, _Float16* __restrict__ W0T,
    const float* __restrict__ W1, _Float16* __restrict__ W1T,
    unsigned* __restrict__ maxdz)
{
    int id = blockIdx.x * 256 + threadIdx.x;   // 0..4607
    if (id < 512) maxdz[id] = 0u;              // maxd0+maxd1 keys (= -inf)
    const float* W; _Float16* WT; int KT, task;
    if (id < 512) { W = W0; WT = W0T; KT = 64;  task = id; }
    else          { W = W1; WT = W1T; KT = 512; task = id - 512; }
    int n = task & 63, gabs = task >> 6;
    int c = gabs >> 3, g = gabs & 7;
    f16x8 hv;
#pragma unroll
    for (int e = 0; e < 8; ++e)
        hv[e] = (_Float16)W[(size_t)(gabs * 8 + e) * 64 + n];
    *(f16x8*)(WT + (size_t)n * KT + c * 64 + (g ^ (n & 7)) * 8) = hv;
}

// ============ shared epilogue: 16x66 ctile -> s, dTg, hpT, maxd atomic ======
static __device__ __forceinline__ void epi_sd_hpt(
    const float* ctile, const float* asd_f, int row0, int t,
    float* __restrict__ s, float* __restrict__ dTg, _Float16* __restrict__ hpT,
    float* dmax_lds, unsigned* __restrict__ maxd_out)
{
    int b = row0 >> 9, jb = row0 & 511;
    if (t < 128) {
        int rr = t >> 3, h = t & 7;
        float sv = 0.f, dv = 0.f;
#pragma unroll
        for (int f = 0; f < 64; ++f) {
            float hv = ctile[rr * 66 + f];
            sv = fmaf(hv, asd_f[f * 8 + h], sv);
            dv = fmaf(hv, asd_f[512 + f * 8 + h], dv);
        }
        s[((size_t)b * NN + jb + rr) * 8 + h] = sv;
        dTg[((size_t)b * 8 + h) * NN + jb + rr] = dv;
        dmax_lds[t] = dv;
    } else if (t < 256) {
        int t2 = t - 128;
        int f = t2 >> 1, jl = (t2 & 1) * 8;
        f16x8 hv;
#pragma unroll
        for (int e = 0; e < 8; ++e)
            hv[e] = (_Float16)ctile[(jl + e) * 66 + f];
        *(f16x8*)(hpT + ((size_t)b * 64 + f) * NN + jb + jl) = hv;
    }
    __syncthreads();
    if (t < 8) {
        float m = dmax_lds[t];
#pragma unroll
        for (int k = 1; k < 16; ++k) m = fmaxf(m, dmax_lds[t + 8 * k]);
        atomicMax(maxd_out + (b * 8 + t), fenc(m));
    }
}

// ============ Layer-0 GEMM + adj bit-mask prep ==============================
__global__ __launch_bounds__(256) void k_gemm0(
    const float* __restrict__ x, const _Float16* __restrict__ W0T,
    const float* __restrict__ a_src, const float* __restrict__ a_dst,
    const float* __restrict__ adj, unsigned long long* __restrict__ adjb,
    float* __restrict__ s, float* __restrict__ dTg, _Float16* __restrict__ hpT,
    unsigned* __restrict__ maxd)
{
    __shared__ float ctile[16 * 66];
    __shared__ float asd_f[1024];
    __shared__ unsigned int mrow[16][16];
    __shared__ float dmax[128];
    int t = threadIdx.x, row0 = blockIdx.x * 16;
    int lane = t & 63, w = t >> 6, cn = lane & 15, rq = lane >> 4;

    // ---- issue adj loads early: thread t covers row (t>>4), j in [seg*32,+32)
    int ar = t >> 4, seg = t & 15;
    const float* ap = adj + (size_t)(row0 + ar) * NN + seg * 32;
    float4 av[8];
#pragma unroll
    for (int q = 0; q < 8; ++q) av[q] = ((const float4*)ap)[q];

    ((float4*)asd_f)[t] = (t < 128) ? ((const float4*)a_src)[t]
                                    : ((const float4*)a_dst)[t - 128];
    f32x4 acc;
#pragma unroll
    for (int e = 0; e < 4; ++e) acc[e] = 0.f;
#pragma unroll
    for (int ks = 0; ks < 2; ++ks) {
        const float* xp = x + (size_t)(row0 + cn) * 64 + ks * 32 + rq * 8;
        float4 x0 = *(const float4*)xp, x1 = *(const float4*)(xp + 4);
        f16x8 ah = {(_Float16)x0.x, (_Float16)x0.y, (_Float16)x0.z, (_Float16)x0.w,
                    (_Float16)x1.x, (_Float16)x1.y, (_Float16)x1.z, (_Float16)x1.w};
        int nn = w * 16 + cn;
        f16x8 bh = *(const f16x8*)(W0T + (size_t)nn * 64 + (((ks * 4 + rq) ^ (nn & 7)) * 8));
        acc = MFMA16(ah, bh, acc);
    }
#pragma unroll
    for (int r = 0; r < 4; ++r)
        ctile[(rq * 4 + r) * 66 + w * 16 + cn] = acc[r];
    __syncthreads();
    epi_sd_hpt(ctile, asd_f, row0, t, s, dTg, hpT, dmax, maxd);

    // ---- pack 32 adj entries -> u32 bits, fold self-loop, assemble u64s
    unsigned int m32 = 0;
#pragma unroll
    for (int q = 0; q < 8; ++q) {
        if (av[q].x != 0.f) m32 |= 1u << (q * 4 + 0);
        if (av[q].y != 0.f) m32 |= 1u << (q * 4 + 1);
        if (av[q].z != 0.f) m32 |= 1u << (q * 4 + 2);
        if (av[q].w != 0.f) m32 |= 1u << (q * 4 + 3);
    }
    int i = (row0 + ar) & (NN - 1);
    if ((i >> 5) == seg) m32 |= 1u << (i & 31);
    mrow[ar][seg] = m32;
    __syncthreads();
    if (t < 128) {
        int r = t >> 3, k = t & 7;
        unsigned long long u = (unsigned long long)mrow[r][2 * k]
                             | ((unsigned long long)mrow[r][2 * k + 1] << 32);
        adjb[(size_t)(row0 + r) * 8 + k] = u;
    }
}

// ============ fused attention v9b: 8 waves, ONE HEAD PER WAVE ===============
// 512-thread blocks, wave w owns head w for the 16-row tile -> 32 waves/CU
// (8/SIMD at the 64-VGPR cap). LDS: 2 x (8KB hT + 2KB dd) = 20.5KB.
// v9 BUG FIXED: wave staging base is (w<<9) fp16 elems (1024B/wave: 8 rows x
// 128B), NOT (w<<10) — v9 had waves 4-7 clobbering dd/bufQ -> NaN.
// hT + dd staged via global_load_lds double-buffer, 1 barrier per 64-j chunk.
// gemm1: 8 waves K-split (w,w+4 share col-tile), partials summed in LDS.
#define PSTEP(DDv, MBYTE, KS, HTC)                                      \
    do {                                                                \
        AF aA;                                                          \
        _Pragma("unroll")                                               \
        for (int e = 0; e < 8; e += 2) {                                \
            float pA[2];                                                \
            _Pragma("unroll")                                           \
            for (int q = 0; q < 2; ++q) {                               \
                int ee = e + q;                                         \
                bool con = (MBYTE >> ee) & 1u;                          \
                float e0 = sv + DDv[ee];                                \
                float l0 = fmaxf(e0, 0.2f * e0);                        \
                float p0 = __expf(l0 - M);                              \
                pA[q] = (con && l0 != 0.f) ? p0 : 0.f;                  \
            }                                                           \
            fp16x2 ka = __builtin_amdgcn_cvt_pkrtz(pA[0], pA[1]);       \
            aA.u[e >> 1] = __builtin_bit_cast(unsigned int, ka);        \
        }                                                               \
        accrs = MFMA16(aA.v, ones, accrs);                              \
        _Pragma("unroll")                                               \
        for (int ft = 0; ft < 4; ++ft) {                                \
            int f = ft * 16 + cn;                                       \
            f16x8 bh = *(const f16x8*)&HTC[f * 64 + ((((KS) * 4 + rq) ^ (f & 7)) * 8)]; \
            acc[ft] = MFMA16(aA.v, bh, acc[ft]);                        \
        }                                                               \
    } while (0)

template<int MODE>
__global__ __launch_bounds__(512, 8) void k_attn_fused(
    const unsigned long long* __restrict__ adjb, const float* __restrict__ s,
    const float* __restrict__ dTg, const unsigned* __restrict__ maxd,
    const _Float16* __restrict__ hpT,
    const _Float16* __restrict__ W1T,
    const float* __restrict__ a_src, const float* __restrict__ a_dst,
    float* __restrict__ s_out, float* __restrict__ dTg_out,
    _Float16* __restrict__ hpT_out, unsigned* __restrict__ maxd_out,
    float* __restrict__ o_f)
{
    __shared__ __align__(16) char smem[20480];
    char* bufP = smem;                         // 8KB hT + 2KB dd
    char* bufQ = smem + 10240;

    int blk = blockIdx.x;
    int vb = ((blk & 7) << 7) | (blk >> 3);    // XCD swizzle: 4 batches/XCD
    int b = vb >> 5, i0 = (vb & 31) << 4;
    int row0 = vb * 16;                        // = b*512 + i0
    int t = threadIdx.x, lane = t & 63, w = t >> 6;   // w = head (0..7)
    int cn = lane & 15, rq = lane >> 4;
    int myrow = i0 + cn;

    const _Float16* hb = hpT + (size_t)b * 64 * NN;
    // hT staging: 512 threads cover all 64 rows; source pre-swizzled granule.
    // Wave w covers rows 8w..8w+7 -> base (w<<9) fp16 elems (= 1024B/wave).
    int f0 = t >> 3, g0 = t & 7;               // f0 in [0,64)
    const _Float16* hsrc = hb + (size_t)f0 * NN + ((g0 ^ (f0 & 7)) * 8);
    // dd staging: wave w stages head w, full wave, 4B/lane
    const float* dsrc = dTg + ((size_t)b * 8 + w) * NN + lane;

    {   // prologue: stage chunk 0 into bufP
        gload_lds16(hsrc, (_Float16*)bufP + (w << 9));
        gload_lds4(dsrc, (float*)(bufP + 8192) + (w << 6));
    }

    float sv = s[((size_t)b * NN + myrow) * 8 + w];
    float md = fdec(maxd[b * 8 + w]);
    float M = fmaxf(sv + md, 0.f);
    const unsigned long long* abr = adjb + ((size_t)b * NN + myrow) * 8;
    int rq8 = rq * 8;

    f16x8 ones;
#pragma unroll
    for (int e = 0; e < 8; ++e) ones[e] = (_Float16)1.0f;

    f32x4 acc[4], accrs;
#pragma unroll
    for (int e = 0; e < 4; ++e) accrs[e] = 0.f;
#pragma unroll
    for (int ft = 0; ft < 4; ++ft)
#pragma unroll
        for (int e = 0; e < 4; ++e) acc[ft][e] = 0.f;

    unsigned long long mb = abr[0];
    __syncthreads();                           // buf0 staged

    for (int jcx = 0; jcx < 8; ++jcx) {
        int jc = jcx * 64;
        char* cur = (jcx & 1) ? bufQ : bufP;
        char* nxt = (jcx & 1) ? bufP : bufQ;
        if (jcx < 7) {                         // stage NEXT chunk into idle buf
            gload_lds16(hsrc + jc + 64, (_Float16*)nxt + (w << 9));
            gload_lds4(dsrc + jc + 64, (float*)(nxt + 8192) + (w << 6));
        }
        unsigned long long mbn = (jcx < 7) ? abr[jcx + 1] : 0ull;
        const _Float16* hTc = (const _Float16*)cur;
        const float* ddl = (const float*)(cur + 8192) + (w << 6);
        unsigned int ml = (unsigned int)mb, mh = (unsigned int)(mb >> 32);
#pragma unroll
        for (int ks = 0; ks < 2; ++ks) {
            float dd[8];
            *(float4*)&dd[0] = *(const float4*)(ddl + ks * 32 + rq8);
            *(float4*)&dd[4] = *(const float4*)(ddl + ks * 32 + rq8 + 4);
            unsigned int mby = ((ks ? mh : ml) >> rq8) & 0xffu;
            PSTEP(dd, mby, ks, hTc);
        }
        mb = mbn;
        __syncthreads();                       // drains next-chunk staging too
    }

    float invr[4];
#pragma unroll
    for (int r = 0; r < 4; ++r) invr[r] = 1.0f / accrs[r];

    if (MODE == 0) {
        // ---- x1 tile for head w (normalized + ELU), A-layout, XOR-swizzled
        _Float16* x1all = (_Float16*)smem;     // [8 heads][16*64] fp16 = 16KB
#pragma unroll
        for (int ft = 0; ft < 4; ++ft)
#pragma unroll
            for (int r = 0; r < 4; ++r) {
                int il = rq * 4 + r;
                float v = acc[ft][r] * invr[r];
                v = v > 0.f ? v : __expf(v) - 1.f;   // ELU
                int f = ft * 16 + cn;
                x1all[w * 1024 + il * 64 + (((f >> 3) ^ (il & 7)) * 8) + (f & 7)] =
                    (_Float16)v;
            }
        __syncthreads();
        // ---- gemm1: col-tile (w&3), K-half (w>>2); B direct from L2 W1T
        f32x4 g1;
#pragma unroll
        for (int e = 0; e < 4; ++e) g1[e] = 0.f;
        int nn = (w & 3) * 16 + cn, kh = w >> 2;
        const _Float16* wb = W1T + (size_t)nn * 512;
#pragma unroll
        for (int kc2 = 0; kc2 < 4; ++kc2) {
            int kc = kh * 4 + kc2;
#pragma unroll
            for (int ks = 0; ks < 2; ++ks) {
                f16x8 ah = *(const f16x8*)&x1all[kc * 1024 + cn * 64 +
                                                 (((ks * 4 + rq) ^ (cn & 7)) * 8)];
                f16x8 bh = *(const f16x8*)(wb + kc * 64 +
                                           (((ks * 4 + rq) ^ (nn & 7)) * 8));
                g1 = MFMA16(ah, bh, g1);
            }
        }
        __syncthreads();                       // x1all reads done
        float* ct = (float*)smem;              // [2][16*66] partials, 8448B
        float* asd_f = (float*)(smem + 12288); // 4096B
        float* dmax = (float*)(smem + 16384);  // 512B
#pragma unroll
        for (int r = 0; r < 4; ++r)
            ct[kh * 1056 + (rq * 4 + r) * 66 + nn] = g1[r];
        if (t < 256)
            ((float4*)asd_f)[t] = (t < 128) ? ((const float4*)a_src)[t]
                                            : ((const float4*)a_dst)[t - 128];
        __syncthreads();
        for (int idx = t; idx < 1056; idx += 512) ct[idx] += ct[1056 + idx];
        __syncthreads();
        epi_sd_hpt(ct, asd_f, row0, t, s_out, dTg_out, hpT_out, dmax, maxd_out);
    } else {
        float* red = (float*)smem;             // [4][16][64] fp32 = 16KB
#pragma unroll
        for (int ph = 0; ph < 2; ++ph) {
            if ((w >> 2) == ph) {
#pragma unroll
                for (int ft = 0; ft < 4; ++ft)
#pragma unroll
                    for (int r = 0; r < 4; ++r) {
                        int il = rq * 4 + r;
                        float v = acc[ft][r] * invr[r];
                        int off = (w & 3) * 1024 + il * 64 + ft * 16 + cn;
                        if (ph == 0) red[off] = v;
                        else         red[off] += v;
                    }
            }
            __syncthreads();
        }
#pragma unroll
        for (int u = 0; u < 2; ++u) {
            int idx = t + u * 512;
            int il = idx >> 6, f = idx & 63;
            float sum = red[il * 64 + f] + red[1024 + il * 64 + f]
                      + red[2048 + il * 64 + f] + red[3072 + il * 64 + f];
            o_f[((size_t)b * NN + i0 + il) * 64 + f] = sum * 0.125f;
        }
    }
}

extern "C" void kernel_launch(void* const* d_in, const int* in_sizes, int n_in,
                              void* d_out, int out_size, void* d_ws, size_t ws_size,
                              hipStream_t stream) {
    const float* x      = (const float*)d_in[0];
    const float* adj    = (const float*)d_in[1];
    const float* W0     = (const float*)d_in[4];
    const float* a_src0 = (const float*)d_in[5];
    const float* a_dst0 = (const float*)d_in[6];
    const float* W1     = (const float*)d_in[7];
    const float* a_src1 = (const float*)d_in[8];
    const float* a_dst1 = (const float*)d_in[9];
    float* out = (float*)d_out;

    float* ws = (float*)d_ws;
    const size_t R = (size_t)BB * NN;            // 16384 rows
    const size_t BHN = (size_t)BB * 8 * NN;      // 131072
    float* s0    = ws;                           // R*8
    float* dTg0  = s0 + R * 8;
    float* s1    = dTg0 + BHN;
    float* dTg1  = s1 + R * 8;
    unsigned* maxd0 = (unsigned*)(dTg1 + BHN);   // 256 keys
    unsigned* maxd1 = maxd0 + 256;               // 256 keys
    _Float16* hp0T = (_Float16*)(maxd1 + 256);   // 32*64*512
    _Float16* hp1T = hp0T + (size_t)BB * 64 * NN;
    _Float16* W0T  = hp1T + (size_t)BB * 64 * NN;   // 64*64
    _Float16* W1T  = W0T + (size_t)64 * 64;         // 64*512
    unsigned long long* adjb = (unsigned long long*)(W1T + (size_t)64 * 512); // 16384*8B

    k_wt_prep<<<18, 256, 0, stream>>>(W0, W0T, W1, W1T, maxd0);
    k_gemm0<<<1024, 256, 0, stream>>>(x, W0T, a_src0, a_dst0, adj, adjb,
                                      s0, dTg0, hp0T, maxd0);
    k_attn_fused<0><<<1024, 512, 0, stream>>>(adjb, s0, dTg0, maxd0, hp0T,
                                              W1T, a_src1, a_dst1,
                                              s1, dTg1, hp1T, maxd1, nullptr);
    k_attn_fused<1><<<1024, 512, 0, stream>>>(adjb, s1, dTg1, maxd1, hp1T,
                                              nullptr, nullptr, nullptr,
                                              nullptr, nullptr, nullptr, nullptr, out);
}